// Round 7
// baseline (139.452 us; speedup 1.0000x reference)
//
#include <hip/hip_runtime.h>

#define B 32
#define E 256
#define N 64
#define KV 100
#define QD 768
#define TILE_F4 1600            // N*KV/4 float4s per (b,e) tile
#define TPB 16                  // tiles per persistent block
#define NBLK ((B * E) / TPB)    // 512 = 2 blocks/CU

// async global->LDS: LDS dst is wave-uniform base (+ lane*16 by HW), src per-lane
#define ASYNC16(gsrc, ldst) \
    __builtin_amdgcn_global_load_lds( \
        (const __attribute__((address_space(1))) void*)(gsrc), \
        (__attribute__((address_space(3))) void*)(ldst), 16, 0, 0)

#define WAITCNT_VM14  asm volatile("s_waitcnt vmcnt(14)" ::: "memory")
#define WAITCNT_LGKM  asm volatile("s_waitcnt lgkmcnt(0)" ::: "memory")
#define BARRIER()     __builtin_amdgcn_s_barrier()

__device__ __forceinline__ float dot4f(float4 a, float4 b) {
    return a.x * b.x + a.y * b.y + a.z * b.z + a.w * b.w;
}

// ---------------------------------------------------------------------------
// Prep: Qk[b][j] = 0.1 * sum_i tanh(q[b]@W_q[i]+b_q[i]) * W_kv[i][j]
// ---------------------------------------------------------------------------
__global__ __launch_bounds__(256) void prep_kernel(
    const float* __restrict__ q, const float* __restrict__ W_q,
    const float* __restrict__ b_q, const float* __restrict__ W_kv,
    float* __restrict__ Qk)
{
    const int tid = threadIdx.x;
    const int b   = blockIdx.x;

    __shared__ float q_lds[QD];
    __shared__ float Qp_lds[KV];

    for (int i = tid; i < QD; i += 256) q_lds[i] = q[b * QD + i];
    __syncthreads();

    const int i = tid >> 1, h = tid & 1;
    if (i < KV) {
        float acc = 0.f;
        const float* wrow = W_q + i * QD + h * (QD / 2);
        const float* qrow = q_lds + h * (QD / 2);
        #pragma unroll 8
        for (int d = 0; d < QD / 2; d++) acc += qrow[d] * wrow[d];
        acc += __shfl_xor(acc, 1);
        if (h == 0) Qp_lds[i] = tanhf(acc + b_q[i]);
    }
    __syncthreads();

    if (tid < KV) {
        float acc = 0.f;
        #pragma unroll 4
        for (int ii = 0; ii < KV; ii++) acc += Qp_lds[ii] * W_kv[ii * KV + tid];
        Qk[b * KV + tid] = acc * 0.1f;   // 1/sqrt(100)
    }
}

// ---------------------------------------------------------------------------
// Main: persistent blocks, 16 tiles each, software-pipelined.
// Per tile per wave: exactly 7 v-DMA (dup tail) + 7 k reg-loads (clamped)
// = 14 VMEM -> counted vmcnt(14) keeps next tile in flight across barriers.
// ---------------------------------------------------------------------------

// issue next tile's loads: v via DMA into VBUF, k into register batch KK
#define ISSUE_TILE(BE, VBUF, KK) do {                                         \
    const float4* vb4_ = (const float4*)(v + (size_t)(BE) * (N * KV));        \
    const float4* kb4_ = (const float4*)(k + (size_t)(BE) * (N * KV));        \
    _Pragma("unroll")                                                         \
    for (int j_ = 0; j_ < 6; j_++) {                                          \
        int i_ = 4 * j_ + wid;                                                \
        ASYNC16(vb4_ + i_ * 64 + lane, (float4*)(VBUF) + i_ * 64);            \
    }                                                                         \
    ASYNC16(vb4_ + 24 * 64 + lane, (float4*)(VBUF) + 24 * 64);                \
    _Pragma("unroll")                                                         \
    for (int r_ = 0; r_ < 7; r_++) {                                          \
        int f_ = r_ * 256 + tid; if (f_ > TILE_F4 - 1) f_ = TILE_F4 - 1;      \
        KK[r_] = kb4_[f_];                                                    \
    }                                                                         \
} while (0)

#define COMPUTE_TILE(TCUR, VBUF, KK) do {                                     \
    { int c_ = c0;                                                            \
      _Pragma("unroll")                                                       \
      for (int r_ = 0; r_ < 7; r_++) {                                        \
        int f_ = r_ * 256 + tid;                                              \
        if (f_ < TILE_F4) {                                                   \
            float4 qq_ = ((const float4*)qk_lds)[c_];                         \
            kpbuf[f_] = dot4f(KK[r_], qq_);                                   \
        }                                                                     \
        c_ += 6; if (c_ >= 25) c_ -= 25;                                      \
      } }                                                                     \
    WAITCNT_LGKM; BARRIER();  /* B1: kpbuf visible */                         \
    if (tid < N) {                                                            \
        float s_ = 0.f;                                                       \
        _Pragma("unroll")                                                     \
        for (int j_ = 0; j_ < 25; j_++) s_ += kpbuf[tid * 25 + j_];           \
        if (s_ == 0.0f) s_ = -10000.0f;       /* masked_fill(att==0) */       \
        s_ = (s_ > 0.0f) ? s_ : 0.01f * s_;   /* leaky_relu */                \
        float m_ = s_;                                                        \
        _Pragma("unroll")                                                     \
        for (int o_ = 32; o_; o_ >>= 1) m_ = fmaxf(m_, __shfl_xor(m_, o_));   \
        float e_ = __expf(s_ - m_);                                           \
        float su_ = e_;                                                       \
        _Pragma("unroll")                                                     \
        for (int o_ = 32; o_; o_ >>= 1) su_ += __shfl_xor(su_, o_);           \
        float r_ = e_ / su_;                                                  \
        if (r_ == 0.015625f) r_ = 0.f;        /* masked_fill(att==1/N) */     \
        att_lds[tid] = r_;                                                    \
    }                                                                         \
    WAITCNT_LGKM; BARRIER();  /* B2: att visible */                           \
    WAITCNT_VM14;             /* tile TCUR's v-DMA done; prefetch survives */ \
    if (tid < KV) {                                                           \
        float a_ = 0.f;                                                       \
        _Pragma("unroll 8")                                                   \
        for (int n_ = 0; n_ < N; n_++)                                        \
            a_ += att_lds[n_] * (VBUF)[n_ * KV + tid];                        \
        agg_out[(size_t)(be0 + (TCUR)) * KV + tid] = a_;                      \
    }                                                                         \
    BARRIER();                /* B3: VBUF free for next DMA target */         \
} while (0)

__global__ __launch_bounds__(256, 2) void attn_main(
    const float* __restrict__ k,    // [B,E,N,KV]
    const float* __restrict__ v,    // [B,E,N,KV]
    const float* __restrict__ Qk,   // [B,KV] pre-scaled
    float* __restrict__ agg_out)    // ws: [B*E, KV]
{
    __shared__ __align__(16) float vbufA[N * KV];   // 25.6 KB
    __shared__ __align__(16) float vbufB[N * KV];   // 25.6 KB
    __shared__ float kpbuf[TILE_F4];                // 6.4 KB
    __shared__ __align__(16) float qk_lds[KV];
    __shared__ float att_lds[N];

    const int tid  = threadIdx.x;
    const int wid  = tid >> 6;
    const int lane = tid & 63;
    const int be0  = blockIdx.x * TPB;
    const int b    = be0 >> 8;          // uniform per block (16 | 256)
    const int c0   = tid % 25;

    // qk load issued oldest; ISSUE(tile0) after -> compiler's wait for the
    // ds_write stays counted (vmcnt(14)), prefetch survives the prologue.
    float4 qkreg = make_float4(0.f, 0.f, 0.f, 0.f);
    if (lane < 25) qkreg = ((const float4*)(Qk + b * KV))[lane];

    float4 kkA[7], kkB[7];
    ISSUE_TILE(be0, vbufA, kkA);

    if (lane < 25) ((float4*)qk_lds)[lane] = qkreg;
    WAITCNT_LGKM;
    BARRIER();   // qk_lds ready (raw barrier: no vmcnt drain)

    #pragma unroll 1
    for (int t = 0; t < TPB; t += 2) {
        ISSUE_TILE(be0 + t + 1, vbufB, kkB);
        COMPUTE_TILE(t, vbufA, kkA);
        int tn = (t + 2 < TPB) ? t + 2 : TPB - 1;   // clamp: uniform counts
        ISSUE_TILE(be0 + tn, vbufA, kkA);
        COMPUTE_TILE(t + 1, vbufB, kkB);
    }
}

// ---------------------------------------------------------------------------
// Projection: out[be][i] = dot(W_v row i, agg[be]); one wave per be.
// ---------------------------------------------------------------------------
__global__ __launch_bounds__(256) void proj_kernel(
    const float* __restrict__ agg,   // [B*E, KV]
    const float* __restrict__ W_v,   // [KV, KV] (L2-hot)
    float* __restrict__ out)         // [B*E, KV]
{
    __shared__ __align__(16) float a_lds[4][KV];
    const int tid = threadIdx.x, wid = tid >> 6, lane = tid & 63;
    const int be  = blockIdx.x * 4 + wid;

    if (lane < 25)
        ((float4*)a_lds[wid])[lane] = ((const float4*)(agg + (size_t)be * KV))[lane];
    // within-wave LDS dep: compiler inserts lgkmcnt

    const float4* wv4 = (const float4*)W_v;
    const float4* a4  = (const float4*)a_lds[wid];
    #pragma unroll
    for (int p = 0; p < 2; p++) {
        const int i = p * 64 + lane;
        if (i < KV) {
            float acc = 0.f;
            #pragma unroll
            for (int j = 0; j < 25; j++) acc += dot4f(wv4[i * 25 + j], a4[j]);
            out[(size_t)be * KV + i] = acc;
        }
    }
}

extern "C" void kernel_launch(void* const* d_in, const int* in_sizes, int n_in,
                              void* d_out, int out_size, void* d_ws, size_t ws_size,
                              hipStream_t stream) {
    // setup_inputs order: input_ent, q, k, v, W_q, b_q, W_kv, W_v
    const float* q    = (const float*)d_in[1];
    const float* k    = (const float*)d_in[2];
    const float* v    = (const float*)d_in[3];
    const float* W_q  = (const float*)d_in[4];
    const float* b_q  = (const float*)d_in[5];
    const float* W_kv = (const float*)d_in[6];
    const float* W_v  = (const float*)d_in[7];
    float* out  = (float*)d_out;

    float* Qk  = (float*)d_ws;                 // B*KV = 3200 floats
    float* agg = Qk + B * KV;                  // B*E*KV = 819200 floats

    prep_kernel<<<B, 256, 0, stream>>>(q, W_q, b_q, W_kv, Qk);
    attn_main<<<NBLK, 256, 0, stream>>>(k, v, Qk, agg);
    proj_kernel<<<(B * E) / 4, 256, 0, stream>>>(agg, W_v, out);
}

// Round 8
// 127.055 us; speedup vs baseline: 1.0976x; 1.0976x over previous
//
#include <hip/hip_runtime.h>

#define B 32
#define E 256
#define N 64
#define KV 100
#define QD 768

// async global->LDS, 16B/lane; LDS dst wave-uniform base, global src per-lane
#define ASYNC16(gsrc, ldst) \
    __builtin_amdgcn_global_load_lds( \
        (const __attribute__((address_space(1))) void*)(gsrc), \
        (__attribute__((address_space(3))) void*)(ldst), 16, 0, 0)

__device__ __forceinline__ float dot4f(float4 a, float4 b) {
    return a.x * b.x + a.y * b.y + a.z * b.z + a.w * b.w;
}

// ---------------------------------------------------------------------------
// Prep: Qk[b][j] = 0.1 * sum_i tanh(q[b]@W_q[i]+b_q[i]) * W_kv[i][j]
// ---------------------------------------------------------------------------
__global__ __launch_bounds__(256) void prep_kernel(
    const float* __restrict__ q, const float* __restrict__ W_q,
    const float* __restrict__ b_q, const float* __restrict__ W_kv,
    float* __restrict__ Qk)
{
    const int tid = threadIdx.x;
    const int b   = blockIdx.x;

    __shared__ float q_lds[QD];
    __shared__ float Qp_lds[KV];

    for (int i = tid; i < QD; i += 256) q_lds[i] = q[b * QD + i];
    __syncthreads();

    const int i = tid >> 1, h = tid & 1;
    if (i < KV) {
        float acc = 0.f;
        const float* wrow = W_q + i * QD + h * (QD / 2);
        const float* qrow = q_lds + h * (QD / 2);
        #pragma unroll 8
        for (int d = 0; d < QD / 2; d++) acc += qrow[d] * wrow[d];
        acc += __shfl_xor(acc, 1);
        if (h == 0) Qp_lds[i] = tanhf(acc + b_q[i]);
    }
    __syncthreads();

    if (tid < KV) {
        float acc = 0.f;
        #pragma unroll 4
        for (int ii = 0; ii < KV; ii++) acc += Qp_lds[ii] * W_kv[ii * KV + tid];
        Qk[b * KV + tid] = acc * 0.1f;   // 1/sqrt(100)
    }
}

// ---------------------------------------------------------------------------
// Main: one block per (b,e), TWO barriers, 25.9 KB LDS -> 6 blocks/CU.
//  - v tile: zero-VGPR global_load_lds (7 DMA/wave, uniform; dup tail chunk)
//  - k tile: quad-pattern float4 reg loads + shfl reduce (no kpbuf, no bar)
//  - Qk: per-lane direct global reads (L1/L2-hot, no LDS, no barrier)
//  - agg -> ws; projection in separate tiny kernel
// ---------------------------------------------------------------------------
__global__ __launch_bounds__(256, 6) void attn_kernel(
    const float* __restrict__ k,    // [B,E,N,KV]
    const float* __restrict__ v,    // [B,E,N,KV]
    const float* __restrict__ Qk,   // [B,KV] pre-scaled by 1/sqrt(KV)
    float* __restrict__ agg_out)    // ws: [B*E, KV]
{
    __shared__ __align__(16) float vbuf[N * KV];    // 25.6 KB
    __shared__ float att_lds[N];                    // 256 B

    const int tid  = threadIdx.x;
    const int wid  = tid >> 6;
    const int lane = tid & 63;
    const int be   = blockIdx.x;
    const int b    = be >> 8;

    const float4* kb4  = (const float4*)(k + (size_t)be * (N * KV));
    const float4* vb4  = (const float4*)(v + (size_t)be * (N * KV));
    const float4* qk4g = (const float4*)(Qk + b * KV);
    float4* vbuf4 = (float4*)vbuf;

    // ---- issue order: k (oldest) -> Qk -> v-DMA (newest, stays in flight) --
    const int n = tid >> 2, sub = tid & 3;         // 64 rows x 4 lanes
    const float4* krow = kb4 + n * (KV / 4);

    float4 kk[7], qq[7];
    #pragma unroll
    for (int i = 0; i < 7; i++) {
        int j = sub + 4 * i; if (j > 24) j = 24;   // clamp (gated below)
        kk[i] = krow[j];
    }
    #pragma unroll
    for (int i = 0; i < 7; i++) {
        int j = sub + 4 * i; if (j > 24) j = 24;
        qq[i] = qk4g[j];                            // L1/L2-hot broadcast-ish
    }
    // v DMA: 7 chunks/wave, uniform count (chunk 24 duplicated by all waves)
    #pragma unroll
    for (int t = 0; t < 6; t++) {
        const int c = wid + 4 * t;                  // wave-uniform
        ASYNC16(vb4 + c * 64 + lane, vbuf4 + c * 64);
    }
    ASYNC16(vb4 + 24 * 64 + lane, vbuf4 + 24 * 64); // dup write, idempotent

    // ---- scores: per-lane partial dots, shfl reduce within quad ----
    {
        float acc = 0.f;
        #pragma unroll
        for (int i = 0; i < 7; i++) {
            float g = (sub + 4 * i <= 24) ? 1.f : 0.f;   // gate clamped slot
            acc += g * dot4f(kk[i], qq[i]);
        }
        acc += __shfl_xor(acc, 1);
        acc += __shfl_xor(acc, 2);
        if (sub == 0) {
            float a = acc;                       // includes 1/sqrt(KV)
            if (a == 0.0f) a = -10000.0f;        // masked_fill(att==0, -1e4)
            a = (a > 0.0f) ? a : 0.01f * a;      // leaky_relu
            att_lds[n] = a;
        }
    }
    __syncthreads();   // B1: att raw ready; also drains v-DMA

    // ---- softmax over N=64 in wave 0 ----
    if (tid < 64) {
        float x = att_lds[tid];
        float m = x;
        #pragma unroll
        for (int o = 32; o; o >>= 1) m = fmaxf(m, __shfl_xor(m, o));
        float e = __expf(x - m);
        float s = e;
        #pragma unroll
        for (int o = 32; o; o >>= 1) s += __shfl_xor(s, o);
        float r = e / s;
        if (r == 0.015625f) r = 0.f;            // masked_fill(att==1/N, 0)
        att_lds[tid] = r;
    }
    __syncthreads();   // B2

    // ---- agg[d] = sum_n att[n] * vbuf[n*100+d]; 100 lanes, conflict-free --
    if (tid < KV) {
        float a = 0.f;
        #pragma unroll 8
        for (int nn = 0; nn < N; nn++)
            a += att_lds[nn] * vbuf[nn * KV + tid];
        agg_out[(size_t)be * KV + tid] = a;
    }
}

// ---------------------------------------------------------------------------
// Projection: out[be][i] = dot(W_v row i, agg[be]); one wave per be.
// ---------------------------------------------------------------------------
__global__ __launch_bounds__(256) void proj_kernel(
    const float* __restrict__ agg,   // [B*E, KV]
    const float* __restrict__ W_v,   // [KV, KV] (L2-hot)
    float* __restrict__ out)         // [B*E, KV]
{
    __shared__ __align__(16) float a_lds[4][KV];
    const int tid = threadIdx.x, wid = tid >> 6, lane = tid & 63;
    const int be  = blockIdx.x * 4 + wid;

    if (lane < 25)
        ((float4*)a_lds[wid])[lane] = ((const float4*)(agg + (size_t)be * KV))[lane];
    // within-wave LDS dep: compiler inserts lgkmcnt

    const float4* wv4 = (const float4*)W_v;
    const float4* a4  = (const float4*)a_lds[wid];
    #pragma unroll
    for (int p = 0; p < 2; p++) {
        const int i = p * 64 + lane;
        if (i < KV) {
            float acc = 0.f;
            #pragma unroll
            for (int j = 0; j < 25; j++) acc += dot4f(wv4[i * 25 + j], a4[j]);
            out[(size_t)be * KV + i] = acc;
        }
    }
}

extern "C" void kernel_launch(void* const* d_in, const int* in_sizes, int n_in,
                              void* d_out, int out_size, void* d_ws, size_t ws_size,
                              hipStream_t stream) {
    // setup_inputs order: input_ent, q, k, v, W_q, b_q, W_kv, W_v
    const float* q    = (const float*)d_in[1];
    const float* k    = (const float*)d_in[2];
    const float* v    = (const float*)d_in[3];
    const float* W_q  = (const float*)d_in[4];
    const float* b_q  = (const float*)d_in[5];
    const float* W_kv = (const float*)d_in[6];
    const float* W_v  = (const float*)d_in[7];
    float* out  = (float*)d_out;

    float* Qk  = (float*)d_ws;                 // B*KV = 3200 floats
    float* agg = Qk + B * KV;                  // B*E*KV = 819200 floats

    prep_kernel<<<B, 256, 0, stream>>>(q, W_q, b_q, W_kv, Qk);
    attn_kernel<<<B * E, 256, 0, stream>>>(k, v, Qk, agg);
    proj_kernel<<<(B * E) / 4, 256, 0, stream>>>(agg, W_v, out);
}

// Round 10
// 109.205 us; speedup vs baseline: 1.2770x; 1.1634x over previous
//
#include <hip/hip_runtime.h>

#define B 32
#define E 256
#define N 64
#define KV 100
#define QD 768
#define NF4 ((N * KV) / 4)     // 1600 float4s per (b,e) tile

typedef float floatx4 __attribute__((ext_vector_type(4)));

// async global->LDS, 16B per lane; dst wave-uniform base, src per-lane
#define ASYNC16(gsrc, ldst) \
    __builtin_amdgcn_global_load_lds( \
        (const __attribute__((address_space(1))) void*)(gsrc), \
        (__attribute__((address_space(3))) void*)(ldst), 16, 0, 0)

__device__ __forceinline__ float dot4f(float4 a, float4 b) {
    return a.x * b.x + a.y * b.y + a.z * b.z + a.w * b.w;
}

__device__ __forceinline__ float4 ntload4(const float4* p) {
    floatx4 r = __builtin_nontemporal_load((const floatx4*)p);  // nt flag
    return make_float4(r.x, r.y, r.z, r.w);
}

// ---------------------------------------------------------------------------
// Prep: Qk[b][j] = 0.1 * sum_i tanh(q[b]@W_q[i]+b_q[i]) * W_kv[i][j]
// ---------------------------------------------------------------------------
__global__ __launch_bounds__(256) void prep_kernel(
    const float* __restrict__ q, const float* __restrict__ W_q,
    const float* __restrict__ b_q, const float* __restrict__ W_kv,
    float* __restrict__ Qk)
{
    const int tid = threadIdx.x;
    const int b   = blockIdx.x;

    __shared__ float q_lds[QD];
    __shared__ float Qp_lds[KV];

    for (int i = tid; i < QD; i += 256) q_lds[i] = q[b * QD + i];
    __syncthreads();

    const int i = tid >> 1, h = tid & 1;
    if (i < KV) {
        float acc = 0.f;
        const float* wrow = W_q + i * QD + h * (QD / 2);
        const float* qrow = q_lds + h * (QD / 2);
        #pragma unroll 8
        for (int d = 0; d < QD / 2; d++) acc += qrow[d] * wrow[d];
        acc += __shfl_xor(acc, 1);
        if (h == 0) Qp_lds[i] = tanhf(acc + b_q[i]);
    }
    __syncthreads();

    if (tid < KV) {
        float acc = 0.f;
        #pragma unroll 4
        for (int ii = 0; ii < KV; ii++) acc += Qp_lds[ii] * W_kv[ii * KV + tid];
        Qk[b * KV + tid] = acc * 0.1f;   // 1/sqrt(100)
    }
}

// ---------------------------------------------------------------------------
// Main (R6 skeleton): one block per (b,e).
//  - k: flat-contiguous 1KB/instr nontemporal reg batch -> kpbuf partials
//  - v: zero-VGPR global_load_lds DMA (in flight across score phase)
//  - 2 barriers; agg -> ws; W_v projection in separate kernel
// ---------------------------------------------------------------------------
__global__ __launch_bounds__(256, 4) void attn_kernel(
    const float* __restrict__ k,    // [B,E,N,KV]
    const float* __restrict__ v,    // [B,E,N,KV]
    const float* __restrict__ Qk,   // [B,KV] pre-scaled by 1/sqrt(KV)
    float* __restrict__ agg_out)    // ws: [B*E, KV]
{
    __shared__ __align__(16) float vbuf[N * KV];     // 25.6 KB
    __shared__ float kpbuf[NF4];                     // 6.4 KB
    __shared__ __align__(16) float qk_lds[4][KV];    // per-wave copy
    __shared__ float att_lds[N];

    const int tid  = threadIdx.x;
    const int wid  = tid >> 6;
    const int lane = tid & 63;
    const int be   = blockIdx.x;
    const int b    = be >> 8;

    const float4* kb4 = (const float4*)(k + (size_t)be * (N * KV));
    const float4* vb4 = (const float4*)(v + (size_t)be * (N * KV));
    float4* vbuf4 = (float4*)vbuf;

    // ---- issue order: qk (oldest) -> k nt-batch -> v DMA ----
    float4 qkreg = make_float4(0.f, 0.f, 0.f, 0.f);
    if (lane < KV / 4) qkreg = ((const float4*)(Qk + b * KV))[lane];

    float4 kk[7];
    #pragma unroll
    for (int r = 0; r < 7; r++) {
        int f = r * 256 + tid; if (f > NF4 - 1) f = NF4 - 1;
        kk[r] = ntload4(kb4 + f);
    }

    // v-tile DMA: zero VGPR, ~26KB in flight per wave
    #pragma unroll
    for (int i = 0; i < 6; i++)
        ASYNC16(vb4 + i * 256 + tid, vbuf4 + i * 256 + (tid & 192));
    if (tid < 64) ASYNC16(vb4 + 1536 + tid, vbuf4 + 1536);

    if (lane < KV / 4) ((float4*)qk_lds[wid])[lane] = qkreg;

    // ---- k dots -> kpbuf (c = f%25 tracked incrementally) ----
    int c = tid % 25;
    #pragma unroll
    for (int r = 0; r < 7; r++) {
        int f = r * 256 + tid;
        if (f < NF4) {
            float4 qq = ((const float4*)qk_lds[wid])[c];
            kpbuf[f] = dot4f(kk[r], qq);
        }
        c += 6; if (c >= 25) c -= 25;
    }
    __syncthreads();   // B1: kpbuf visible; v-DMA drained (vmcnt 0)

    // ---- row-reduce + mask + leaky + softmax (wave 0) ----
    if (tid < N) {
        float s = 0.f;
        #pragma unroll
        for (int j = 0; j < 25; j++) s += kpbuf[tid * 25 + j];
        if (s == 0.0f) s = -10000.0f;        // masked_fill(att==0, -1e4)
        s = (s > 0.0f) ? s : 0.01f * s;      // leaky_relu
        float m = s;
        #pragma unroll
        for (int o = 32; o; o >>= 1) m = fmaxf(m, __shfl_xor(m, o));
        float e = __expf(s - m);
        float su = e;
        #pragma unroll
        for (int o = 32; o; o >>= 1) su += __shfl_xor(su, o);
        float r = e / su;
        if (r == 0.015625f) r = 0.f;         // masked_fill(att==1/N, 0)
        att_lds[tid] = r;
    }
    __syncthreads();   // B2

    // ---- agg[d] = sum_n att[n]*vbuf[n*100+d]; 100 lanes, conflict-free ----
    if (tid < KV) {
        float a = 0.f;
        #pragma unroll 8
        for (int n = 0; n < N; n++)
            a += att_lds[n] * vbuf[n * KV + tid];
        agg_out[(size_t)be * KV + tid] = a;
    }
}

// ---------------------------------------------------------------------------
// Projection: out[be][i] = dot(W_v row i, agg[be]); one wave per be.
// ---------------------------------------------------------------------------
__global__ __launch_bounds__(256) void proj_kernel(
    const float* __restrict__ agg,   // [B*E, KV]
    const float* __restrict__ W_v,   // [KV, KV] (L2-hot)
    float* __restrict__ out)         // [B*E, KV]
{
    __shared__ __align__(16) float a_lds[4][KV];
    const int tid = threadIdx.x, wid = tid >> 6, lane = tid & 63;
    const int be  = blockIdx.x * 4 + wid;

    if (lane < 25)
        ((float4*)a_lds[wid])[lane] = ((const float4*)(agg + (size_t)be * KV))[lane];
    // within-wave LDS dep: compiler inserts lgkmcnt

    const float4* wv4 = (const float4*)W_v;
    const float4* a4  = (const float4*)a_lds[wid];
    #pragma unroll
    for (int p = 0; p < 2; p++) {
        const int i = p * 64 + lane;
        if (i < KV) {
            float acc = 0.f;
            #pragma unroll
            for (int j = 0; j < 25; j++) acc += dot4f(wv4[i * 25 + j], a4[j]);
            out[(size_t)be * KV + i] = acc;
        }
    }
}

extern "C" void kernel_launch(void* const* d_in, const int* in_sizes, int n_in,
                              void* d_out, int out_size, void* d_ws, size_t ws_size,
                              hipStream_t stream) {
    // setup_inputs order: input_ent, q, k, v, W_q, b_q, W_kv, W_v
    const float* q    = (const float*)d_in[1];
    const float* k    = (const float*)d_in[2];
    const float* v    = (const float*)d_in[3];
    const float* W_q  = (const float*)d_in[4];
    const float* b_q  = (const float*)d_in[5];
    const float* W_kv = (const float*)d_in[6];
    const float* W_v  = (const float*)d_in[7];
    float* out  = (float*)d_out;

    float* Qk  = (float*)d_ws;                 // B*KV = 3200 floats
    float* agg = Qk + B * KV;                  // B*E*KV = 819200 floats

    prep_kernel<<<B, 256, 0, stream>>>(q, W_q, b_q, W_kv, Qk);
    attn_kernel<<<B * E, 256, 0, stream>>>(k, v, Qk, agg);
    proj_kernel<<<(B * E) / 4, 256, 0, stream>>>(agg, W_v, out);
}

// Round 11
// 101.565 us; speedup vs baseline: 1.3730x; 1.0752x over previous
//
#include <hip/hip_runtime.h>

#define B 32
#define E 256
#define N 64
#define KV 100
#define QD 768
#define NF4 ((N * KV) / 4)     // 1600 float4s per (b,e) tile

typedef float floatx4 __attribute__((ext_vector_type(4)));

// async global->LDS, 16B per lane; dst wave-uniform base, src per-lane
#define ASYNC16(gsrc, ldst) \
    __builtin_amdgcn_global_load_lds( \
        (const __attribute__((address_space(1))) void*)(gsrc), \
        (__attribute__((address_space(3))) void*)(ldst), 16, 0, 0)

__device__ __forceinline__ float dot4f(float4 a, float4 b) {
    return a.x * b.x + a.y * b.y + a.z * b.z + a.w * b.w;
}

__device__ __forceinline__ float4 ntload4(const float4* p) {
    floatx4 r = __builtin_nontemporal_load((const floatx4*)p);  // nt flag
    return make_float4(r.x, r.y, r.z, r.w);
}

// ---------------------------------------------------------------------------
// Prep: Qk[b][j] = 0.1 * sum_i tanh(q[b]@W_q[i]+b_q[i]) * W_kv[i][j]
// ---------------------------------------------------------------------------
__global__ __launch_bounds__(256) void prep_kernel(
    const float* __restrict__ q, const float* __restrict__ W_q,
    const float* __restrict__ b_q, const float* __restrict__ W_kv,
    float* __restrict__ Qk)
{
    const int tid = threadIdx.x;
    const int b   = blockIdx.x;

    __shared__ float q_lds[QD];
    __shared__ float Qp_lds[KV];

    for (int i = tid; i < QD; i += 256) q_lds[i] = q[b * QD + i];
    __syncthreads();

    const int i = tid >> 1, h = tid & 1;
    if (i < KV) {
        float acc = 0.f;
        const float* wrow = W_q + i * QD + h * (QD / 2);
        const float* qrow = q_lds + h * (QD / 2);
        #pragma unroll 8
        for (int d = 0; d < QD / 2; d++) acc += qrow[d] * wrow[d];
        acc += __shfl_xor(acc, 1);
        if (h == 0) Qp_lds[i] = tanhf(acc + b_q[i]);
    }
    __syncthreads();

    if (tid < KV) {
        float acc = 0.f;
        #pragma unroll 4
        for (int ii = 0; ii < KV; ii++) acc += Qp_lds[ii] * W_kv[ii * KV + tid];
        Qk[b * KV + tid] = acc * 0.1f;   // 1/sqrt(100)
    }
}

// ---------------------------------------------------------------------------
// Main: one block per (b,e), XCD-swizzled. nt k-batch + v-DMA, 3 barriers,
// projection fused (W_v L1-resident per CU across its blocks).
// ---------------------------------------------------------------------------
__global__ __launch_bounds__(256, 4) void attn_kernel(
    const float* __restrict__ k,    // [B,E,N,KV]
    const float* __restrict__ v,    // [B,E,N,KV]
    const float* __restrict__ Qk,   // [B,KV] pre-scaled by 1/sqrt(KV)
    const float* __restrict__ W_v,  // [KV,KV]
    float* __restrict__ out)        // [B,E,KV]
{
    __shared__ __align__(16) float vbuf[N * KV];     // 25.6 KB
    __shared__ float kpbuf[NF4];                     // 6.4 KB
    __shared__ __align__(16) float qk_lds[4][KV];    // per-wave copy
    __shared__ float att_lds[N];
    __shared__ __align__(16) float agg_lds[KV];

    const int tid  = threadIdx.x;
    const int wid  = tid >> 6;
    const int lane = tid & 63;
    // T1: bijective XCD swizzle (8192 % 8 == 0): XCD x gets a contiguous
    // 1024-tile (52.4 MB) range of k and v.
    const int orig = blockIdx.x;
    const int be   = ((orig & 7) << 10) | (orig >> 3);
    const int b    = be >> 8;

    const float4* kb4 = (const float4*)(k + (size_t)be * (N * KV));
    const float4* vb4 = (const float4*)(v + (size_t)be * (N * KV));
    float4* vbuf4 = (float4*)vbuf;

    // ---- issue order: qk (oldest) -> k nt-batch -> v DMA ----
    float4 qkreg = make_float4(0.f, 0.f, 0.f, 0.f);
    if (lane < KV / 4) qkreg = ((const float4*)(Qk + b * KV))[lane];

    float4 kk[7];
    #pragma unroll
    for (int r = 0; r < 7; r++) {
        int f = r * 256 + tid; if (f > NF4 - 1) f = NF4 - 1;
        kk[r] = ntload4(kb4 + f);
    }

    // v-tile DMA: zero VGPR, ~26KB in flight per wave
    #pragma unroll
    for (int i = 0; i < 6; i++)
        ASYNC16(vb4 + i * 256 + tid, vbuf4 + i * 256 + (tid & 192));
    if (tid < 64) ASYNC16(vb4 + 1536 + tid, vbuf4 + 1536);

    if (lane < KV / 4) ((float4*)qk_lds[wid])[lane] = qkreg;

    // ---- k dots -> kpbuf (c = f%25 tracked incrementally) ----
    int c = tid % 25;
    #pragma unroll
    for (int r = 0; r < 7; r++) {
        int f = r * 256 + tid;
        if (f < NF4) {
            float4 qq = ((const float4*)qk_lds[wid])[c];
            kpbuf[f] = dot4f(kk[r], qq);
        }
        c += 6; if (c >= 25) c -= 25;
    }
    __syncthreads();   // B1: kpbuf visible; v-DMA drained (vmcnt 0)

    // ---- row-reduce + mask + leaky + softmax (wave 0) ----
    if (tid < N) {
        float s = 0.f;
        #pragma unroll
        for (int j = 0; j < 25; j++) s += kpbuf[tid * 25 + j];
        if (s == 0.0f) s = -10000.0f;        // masked_fill(att==0, -1e4)
        s = (s > 0.0f) ? s : 0.01f * s;      // leaky_relu
        float m = s;
        #pragma unroll
        for (int o = 32; o; o >>= 1) m = fmaxf(m, __shfl_xor(m, o));
        float e = __expf(s - m);
        float su = e;
        #pragma unroll
        for (int o = 32; o; o >>= 1) su += __shfl_xor(su, o);
        float r = e / su;
        if (r == 0.015625f) r = 0.f;         // masked_fill(att==1/N, 0)
        att_lds[tid] = r;
    }
    __syncthreads();   // B2

    // ---- agg[d] = sum_n att[n]*vbuf[n*100+d]; 100 lanes, conflict-free ----
    if (tid < KV) {
        float a = 0.f;
        #pragma unroll 8
        for (int n = 0; n < N; n++)
            a += att_lds[n] * vbuf[n * KV + tid];
        agg_lds[tid] = a;
    }
    __syncthreads();   // B3

    // ---- fused projection: out[be][i] = dot(W_v row i, agg); 2 lanes/out --
    const int p = tid >> 1, h = tid & 1;
    if (p < KV) {
        const float4* wrow = (const float4*)(W_v + p * KV);  // L1-resident/CU
        const float4* a4   = (const float4*)agg_lds;
        float acc = 0.f;
        #pragma unroll
        for (int j = h; j < KV / 4; j += 2) {
            float4 w = wrow[j];
            float4 a = a4[j];
            acc += w.x * a.x + w.y * a.y + w.z * a.z + w.w * a.w;
        }
        acc += __shfl_xor(acc, 1);
        if (h == 0) out[(size_t)be * KV + p] = acc;
    }
}

extern "C" void kernel_launch(void* const* d_in, const int* in_sizes, int n_in,
                              void* d_out, int out_size, void* d_ws, size_t ws_size,
                              hipStream_t stream) {
    // setup_inputs order: input_ent, q, k, v, W_q, b_q, W_kv, W_v
    const float* q    = (const float*)d_in[1];
    const float* k    = (const float*)d_in[2];
    const float* v    = (const float*)d_in[3];
    const float* W_q  = (const float*)d_in[4];
    const float* b_q  = (const float*)d_in[5];
    const float* W_kv = (const float*)d_in[6];
    const float* W_v  = (const float*)d_in[7];
    float* out  = (float*)d_out;

    float* Qk = (float*)d_ws;            // B*KV = 3200 floats

    prep_kernel<<<B, 256, 0, stream>>>(q, W_q, b_q, W_kv, Qk);
    attn_kernel<<<B * E, 256, 0, stream>>>(k, v, Qk, W_v, out);
}